// Round 1
// baseline (652.952 us; speedup 1.0000x reference)
//
#include <hip/hip_runtime.h>
#include <hip/hip_bf16.h>

// Problem constants (from reference): B=64, S=2048, D_ENC=D_DEC=UNITS=512
#define BATCH 64
#define SEQ   2048
#define DIM   512
#define MROWS (BATCH * SEQ)   // 131072 rows of the big GEMM

typedef short bf16x8 __attribute__((ext_vector_type(8)));
typedef float f32x4  __attribute__((ext_vector_type(4)));

static __device__ __forceinline__ unsigned short f2bf(float f) {
    // round-to-nearest-even fp32 -> bf16
    union { float f; unsigned u; } v; v.f = f;
    unsigned u = v.u;
    u += 0x7FFFu + ((u >> 16) & 1u);
    return (unsigned short)(u >> 16);
}

// ---------------------------------------------------------------------------
// Kernel 0: W1 [k][u] fp32  ->  W1t [u][k] bf16   (512x512, tiny)
// ---------------------------------------------------------------------------
__global__ void prep_w1t_kernel(const float* __restrict__ W1,
                                unsigned short* __restrict__ w1t) {
    int stride = gridDim.x * blockDim.x;
    for (int i = blockIdx.x * blockDim.x + threadIdx.x; i < DIM * DIM; i += stride) {
        int k = i >> 9;        // row of W1
        int u = i & 511;       // col of W1
        w1t[u * DIM + k] = f2bf(W1[i]);
    }
}

// ---------------------------------------------------------------------------
// Kernel 1: pd[b][u] = dec[b,:] @ W2[:,u] + b1[u] + b2[u]     (64x512, tiny)
// ---------------------------------------------------------------------------
__global__ void proj_dec_kernel(const float* __restrict__ dec,
                                const float* __restrict__ W2,
                                const float* __restrict__ b1,
                                const float* __restrict__ b2,
                                float* __restrict__ pd) {
    __shared__ float sdec[DIM];
    const int b = blockIdx.x;
    const int t = threadIdx.x;          // 256 threads
    sdec[t]       = dec[b * DIM + t];
    sdec[t + 256] = dec[b * DIM + t + 256];
    __syncthreads();
    const int u0 = t, u1 = t + 256;
    float a0 = b1[u0] + b2[u0];
    float a1 = b1[u1] + b2[u1];
    for (int k = 0; k < DIM; ++k) {
        float dk = sdec[k];
        a0 += dk * W2[k * DIM + u0];
        a1 += dk * W2[k * DIM + u1];
    }
    pd[b * DIM + u0] = a0;
    pd[b * DIM + u1] = a1;
}

// ---------------------------------------------------------------------------
// Kernel 2: fused  score[m] += sum_u tanh( (enc@W1)[m,u] + pd[b,u] ) * V[u]
// 128x128 tile bf16 MFMA GEMM (m93-style register staging; enc is fp32 so we
// convert during staging). Grid: (M/128, 512/128). Epilogue reduces over the
// block's 128 u-columns and atomically adds the partial into scores[m].
// ---------------------------------------------------------------------------
#define BM 128
#define BN 128
#define BK 64
#define SAS 72   // LDS row stride in bf16 elems: 144 B = 9 quad-banks -> conflict-free frag reads

__global__ __launch_bounds__(256, 2) void gemm_score_kernel(
    const float* __restrict__ enc,
    const unsigned short* __restrict__ w1t,   // [u][k] bf16
    const float* __restrict__ pd,             // [b][u]
    const float* __restrict__ V,              // [u]
    float* __restrict__ scores)               // [M] pre-zeroed
{
    __shared__ unsigned short sA[BM * SAS];   // 18432 B
    __shared__ unsigned short sB[BN * SAS];   // 18432 B

    const int tid  = threadIdx.x;
    const int lane = tid & 63;
    const int wave = tid >> 6;
    const int wm   = wave & 1;    // wave row-block (0..1) -> 64 rows
    const int wn   = wave >> 1;   // wave col-block (0..1) -> 64 cols
    const int quad = lane >> 4;
    const int l15  = lane & 15;

    const int row0 = blockIdx.x * BM;   // gridDim.x = 1024
    const int col0 = blockIdx.y * BN;   // gridDim.y = 4

    f32x4 acc[4][4];
    for (int i = 0; i < 4; ++i)
        for (int j = 0; j < 4; ++j)
            acc[i][j] = (f32x4){0.f, 0.f, 0.f, 0.f};

    for (int k0 = 0; k0 < DIM; k0 += BK) {
        // --- stage A: enc tile 128 x 64 fp32 -> bf16 (2048 float4 slots) ---
        for (int i = 0; i < 8; ++i) {
            int s  = i * 256 + tid;
            int r  = s >> 4;         // 16 float4 per row
            int c4 = s & 15;
            const float4 v = *(const float4*)(enc + (size_t)(row0 + r) * DIM + k0 + c4 * 4);
            ushort4 p;
            p.x = f2bf(v.x); p.y = f2bf(v.y); p.z = f2bf(v.z); p.w = f2bf(v.w);
            *(ushort4*)(&sA[r * SAS + c4 * 4]) = p;
        }
        // --- stage B: w1t tile 128 x 64 bf16 (1024 16B chunks) ---
        for (int i = 0; i < 4; ++i) {
            int s  = i * 256 + tid;
            int u  = s >> 3;         // 8 chunks per row
            int c8 = s & 7;
            const uint4 w = *(const uint4*)(w1t + (size_t)(col0 + u) * DIM + k0 + c8 * 8);
            *(uint4*)(&sB[u * SAS + c8 * 8]) = w;
        }
        __syncthreads();

        for (int kk = 0; kk < BK; kk += 32) {
            bf16x8 af[4], bfr[4];
            for (int t4 = 0; t4 < 4; ++t4) {
                int am = wm * 64 + t4 * 16 + l15;
                af[t4]  = *(const bf16x8*)(&sA[am * SAS + kk + quad * 8]);
                int bn = wn * 64 + t4 * 16 + l15;
                bfr[t4] = *(const bf16x8*)(&sB[bn * SAS + kk + quad * 8]);
            }
            for (int tr = 0; tr < 4; ++tr)
                for (int tc = 0; tc < 4; ++tc)
                    acc[tr][tc] = __builtin_amdgcn_mfma_f32_16x16x32_bf16(
                        af[tr], bfr[tc], acc[tr][tc], 0, 0, 0);
        }
        __syncthreads();
    }

    // --- epilogue: tanh + V-dot, reduce over this block's 128 u's ---
    const int b = row0 >> 11;   // SEQ = 2048; 128-row tiles never cross a batch
    float sacc[4][4];
    for (int tr = 0; tr < 4; ++tr)
        for (int r = 0; r < 4; ++r) sacc[tr][r] = 0.f;

    for (int tc = 0; tc < 4; ++tc) {
        int u_g   = col0 + wn * 64 + tc * 16 + l15;   // C/D col = lane&15
        float pdv = pd[b * DIM + u_g];
        float vv  = V[u_g];
        for (int tr = 0; tr < 4; ++tr) {
            for (int r = 0; r < 4; ++r) {
                float feat = tanhf(acc[tr][tc][r] + pdv);
                sacc[tr][r] += feat * vv;
            }
        }
    }
    // reduce across the 16 col-lanes (lane bits 0..3)
    for (int tr = 0; tr < 4; ++tr)
        for (int r = 0; r < 4; ++r) {
            float v = sacc[tr][r];
            v += __shfl_xor(v, 1);
            v += __shfl_xor(v, 2);
            v += __shfl_xor(v, 4);
            v += __shfl_xor(v, 8);
            sacc[tr][r] = v;
        }
    if (l15 == 0) {
        for (int tr = 0; tr < 4; ++tr)
            for (int r = 0; r < 4; ++r) {
                int m_g = row0 + wm * 64 + tr * 16 + quad * 4 + r;  // C/D row
                atomicAdd(&scores[m_g], sacc[tr][r]);
            }
    }
}

// ---------------------------------------------------------------------------
// Kernel 3: per-batch softmax over S=2048 -> attn (written to d_out)
// bv omitted: softmax is shift-invariant, so bv cancels in both outputs.
// ---------------------------------------------------------------------------
__global__ void softmax_kernel(const float* __restrict__ scores,
                               float* __restrict__ attn) {
    __shared__ float se[SEQ];
    __shared__ float red[256];
    const int b = blockIdx.x;
    const int t = threadIdx.x;
    const float* sc = scores + (size_t)b * SEQ;

    float v[8];
    float mx = -1e30f;
    for (int i = 0; i < 8; ++i) {
        v[i] = sc[t + i * 256];
        mx = fmaxf(mx, v[i]);
    }
    red[t] = mx;
    __syncthreads();
    for (int off = 128; off > 0; off >>= 1) {
        if (t < off) red[t] = fmaxf(red[t], red[t + off]);
        __syncthreads();
    }
    mx = red[0];
    __syncthreads();

    float sum = 0.f;
    for (int i = 0; i < 8; ++i) {
        float e = expf(v[i] - mx);
        se[t + i * 256] = e;
        sum += e;
    }
    red[t] = sum;
    __syncthreads();
    for (int off = 128; off > 0; off >>= 1) {
        if (t < off) red[t] += red[t + off];
        __syncthreads();
    }
    const float inv = 1.0f / red[0];
    for (int i = 0; i < 8; ++i)
        attn[(size_t)b * SEQ + t + i * 256] = se[t + i * 256] * inv;
}

// ---------------------------------------------------------------------------
// Kernel 4: context[b][d] = sum_s attn[b,s] * enc[b,s,d]
// Grid (32 s-chunks of 64, 64 batches); atomicAdd into zeroed ctx.
// ---------------------------------------------------------------------------
#define SCHUNK 64
__global__ void context_kernel(const float* __restrict__ enc,
                               const float* __restrict__ attn,
                               float* __restrict__ ctx) {
    __shared__ float sa[SCHUNK];
    const int c = blockIdx.x;   // 0..31
    const int b = blockIdx.y;   // 0..63
    const int t = threadIdx.x;  // 256
    if (t < SCHUNK) sa[t] = attn[(size_t)b * SEQ + c * SCHUNK + t];
    __syncthreads();
    float a0 = 0.f, a1 = 0.f;
    const float* base = enc + ((size_t)b * SEQ + (size_t)c * SCHUNK) * DIM;
    for (int j = 0; j < SCHUNK; ++j) {
        float w = sa[j];
        a0 += w * base[(size_t)j * DIM + t];
        a1 += w * base[(size_t)j * DIM + t + 256];
    }
    atomicAdd(&ctx[b * DIM + t], a0);
    atomicAdd(&ctx[b * DIM + t + 256], a1);
}

// ---------------------------------------------------------------------------
// Launch
// ---------------------------------------------------------------------------
extern "C" void kernel_launch(void* const* d_in, const int* in_sizes, int n_in,
                              void* d_out, int out_size, void* d_ws, size_t ws_size,
                              hipStream_t stream) {
    const float* enc = (const float*)d_in[0];   // [64,2048,512]
    const float* dec = (const float*)d_in[1];   // [64,512]
    const float* W1  = (const float*)d_in[2];   // [512,512]
    const float* b1  = (const float*)d_in[3];   // [512]
    const float* W2  = (const float*)d_in[4];   // [512,512]
    const float* b2  = (const float*)d_in[5];   // [512]
    const float* V   = (const float*)d_in[6];   // [512,1]
    // d_in[7] = bv: dead (softmax shift-invariance)

    float* out  = (float*)d_out;
    float* ctx  = out;                 // [64,512]
    float* attn = out + BATCH * DIM;   // [64,2048]

    char* ws = (char*)d_ws;
    float* pd              = (float*)ws;                        // 131072 B
    unsigned short* w1t    = (unsigned short*)(ws + 131072);    // 524288 B
    float* scores          = (float*)(ws + 131072 + 524288);    // 524288 B

    hipMemsetAsync(scores, 0, (size_t)MROWS * 4, stream);
    hipMemsetAsync(ctx, 0, (size_t)BATCH * DIM * 4, stream);

    prep_w1t_kernel<<<256, 256, 0, stream>>>(W1, w1t);
    proj_dec_kernel<<<BATCH, 256, 0, stream>>>(dec, W2, b1, b2, pd);
    gemm_score_kernel<<<dim3(MROWS / BM, DIM / BN), 256, 0, stream>>>(
        enc, w1t, pd, V, scores);
    softmax_kernel<<<BATCH, 256, 0, stream>>>(scores, attn);
    context_kernel<<<dim3(SEQ / SCHUNK, BATCH), 256, 0, stream>>>(enc, attn, ctx);
}

// Round 2
// 592.699 us; speedup vs baseline: 1.1017x; 1.1017x over previous
//
#include <hip/hip_runtime.h>
#include <hip/hip_bf16.h>

// Problem constants (from reference): B=64, S=2048, D_ENC=D_DEC=UNITS=512
#define BATCH 64
#define SEQ   2048
#define DIM   512
#define MROWS (BATCH * SEQ)   // 131072 rows of the big GEMM

typedef short bf16x8 __attribute__((ext_vector_type(8)));
typedef float f32x4  __attribute__((ext_vector_type(4)));

static __device__ __forceinline__ unsigned short f2bf(float f) {
    // round-to-nearest-even fp32 -> bf16
    union { float f; unsigned u; } v; v.f = f;
    unsigned u = v.u;
    u += 0x7FFFu + ((u >> 16) & 1u);
    return (unsigned short)(u >> 16);
}
static __device__ __forceinline__ float bf2f(unsigned short h) {
    union { unsigned u; float f; } v; v.u = ((unsigned)h) << 16; return v.f;
}

// global -> LDS async DMA, 16B per lane. LDS dest must be wave-uniform base
// + lane*16 (m104/m108 caveat) — our chunk ids are lane-consecutive.
typedef __attribute__((address_space(1))) const unsigned int gu32;
typedef __attribute__((address_space(3))) unsigned int lu32;
static __device__ __forceinline__ void gload_lds16(const unsigned short* g,
                                                   unsigned short* l) {
    __builtin_amdgcn_global_load_lds((gu32*)g, (lu32*)l, 16, 0, 0);
}

// ---------------------------------------------------------------------------
// Kernel 0: W1 [k][u] fp32  ->  W1t [u][k] bf16   (512x512, tiny)
// ---------------------------------------------------------------------------
__global__ void prep_w1t_kernel(const float* __restrict__ W1,
                                unsigned short* __restrict__ w1t) {
    int stride = gridDim.x * blockDim.x;
    for (int i = blockIdx.x * blockDim.x + threadIdx.x; i < DIM * DIM; i += stride) {
        int k = i >> 9;
        int u = i & 511;
        w1t[u * DIM + k] = f2bf(W1[i]);
    }
}

// ---------------------------------------------------------------------------
// Kernel 0b: enc fp32 -> encb bf16 (pure-BW pass: 268 MB R + 134 MB W)
// ---------------------------------------------------------------------------
__global__ void conv_enc_kernel(const float* __restrict__ enc,
                                unsigned short* __restrict__ encb) {
    const size_t nunits = (size_t)MROWS * DIM / 8;  // 8 elems per unit
    size_t stride = (size_t)gridDim.x * blockDim.x;
    for (size_t u = (size_t)blockIdx.x * blockDim.x + threadIdx.x; u < nunits;
         u += stride) {
        const float4* p = (const float4*)(enc + u * 8);
        float4 a = p[0], b = p[1];
        union { ushort4 s[2]; uint4 q; } o;
        o.s[0].x = f2bf(a.x); o.s[0].y = f2bf(a.y);
        o.s[0].z = f2bf(a.z); o.s[0].w = f2bf(a.w);
        o.s[1].x = f2bf(b.x); o.s[1].y = f2bf(b.y);
        o.s[1].z = f2bf(b.z); o.s[1].w = f2bf(b.w);
        *(uint4*)(encb + u * 8) = o.q;
    }
}

// ---------------------------------------------------------------------------
// Kernel 1: pd[b][u] = dec[b,:] @ W2[:,u] + b1[u] + b2[u]     (64x512, tiny)
// ---------------------------------------------------------------------------
__global__ void proj_dec_kernel(const float* __restrict__ dec,
                                const float* __restrict__ W2,
                                const float* __restrict__ b1,
                                const float* __restrict__ b2,
                                float* __restrict__ pd) {
    __shared__ float sdec[DIM];
    const int b = blockIdx.x;
    const int t = threadIdx.x;          // 256 threads
    sdec[t]       = dec[b * DIM + t];
    sdec[t + 256] = dec[b * DIM + t + 256];
    __syncthreads();
    const int u0 = t, u1 = t + 256;
    float a0 = b1[u0] + b2[u0];
    float a1 = b1[u1] + b2[u1];
    for (int k = 0; k < DIM; ++k) {
        float dk = sdec[k];
        a0 += dk * W2[k * DIM + u0];
        a1 += dk * W2[k * DIM + u1];
    }
    pd[b * DIM + u0] = a0;
    pd[b * DIM + u1] = a1;
}

// ---------------------------------------------------------------------------
// Kernel 2 (fast): m97-style bf16 MFMA GEMM with global_load_lds staging and
// XOR chunk swizzle (source-address permute keeps DMA contiguity, makes frag
// ds_read_b128 conflict-free). Fused tanh + V-dot epilogue -> scores.
// Grid (4 col-tiles, 1024 row-tiles): col-siblings dispatch-adjacent for L2/L3
// reuse of the A strip.
// ---------------------------------------------------------------------------
#define BM 128
#define BN 128
#define BK 64

__global__ __launch_bounds__(256, 2) void gemm_score_fast(
    const unsigned short* __restrict__ encb,  // [m][k] bf16
    const unsigned short* __restrict__ w1t,   // [u][k] bf16
    const float* __restrict__ pd,             // [b][u]
    const float* __restrict__ V,              // [u]
    float* __restrict__ scores)               // [M] pre-zeroed
{
    __shared__ unsigned short sA[BM * BK];   // 16 KB, rows of 128 B, no pad
    __shared__ unsigned short sB[BN * BK];   // 16 KB

    const int tid  = threadIdx.x;
    const int lane = tid & 63;
    const int wave = tid >> 6;
    const int wm   = wave & 1;
    const int wn   = wave >> 1;
    const int quad = lane >> 4;
    const int l15  = lane & 15;

    const int col0 = blockIdx.x * BN;   // gridDim.x = 4
    const int row0 = blockIdx.y * BM;   // gridDim.y = 1024

    f32x4 acc[4][4];
    for (int i = 0; i < 4; ++i)
        for (int j = 0; j < 4; ++j)
            acc[i][j] = (f32x4){0.f, 0.f, 0.f, 0.f};

    for (int k0 = 0; k0 < DIM; k0 += BK) {
        // stage A+B: 1024 chunks x 16 B each, 4 per thread per tile.
        // LDS slot (r, cc) holds global chunk (r, cc ^ (r&7)).
        for (int i = 0; i < 4; ++i) {
            int c  = i * 256 + tid;
            int r  = c >> 3;
            int cc = c & 7;
            int gc = cc ^ (r & 7);
            gload_lds16(encb + (size_t)(row0 + r) * DIM + k0 + gc * 8, &sA[c * 8]);
        }
        for (int i = 0; i < 4; ++i) {
            int c  = i * 256 + tid;
            int r  = c >> 3;
            int cc = c & 7;
            int gc = cc ^ (r & 7);
            gload_lds16(w1t + (size_t)(col0 + r) * DIM + k0 + gc * 8, &sB[c * 8]);
        }
        __syncthreads();

        for (int kk = 0; kk < BK; kk += 32) {
            bf16x8 af[4], bfr[4];
            for (int t4 = 0; t4 < 4; ++t4) {
                int am = wm * 64 + t4 * 16 + l15;
                int jc = (kk >> 3) + quad;                  // global chunk 0..7
                af[t4]  = *(const bf16x8*)(&sA[am * BK + ((jc ^ (am & 7)) * 8)]);
                int bn = wn * 64 + t4 * 16 + l15;
                bfr[t4] = *(const bf16x8*)(&sB[bn * BK + ((jc ^ (bn & 7)) * 8)]);
            }
            for (int tr = 0; tr < 4; ++tr)
                for (int tc = 0; tc < 4; ++tc)
                    acc[tr][tc] = __builtin_amdgcn_mfma_f32_16x16x32_bf16(
                        af[tr], bfr[tc], acc[tr][tc], 0, 0, 0);
        }
        __syncthreads();
    }

    // epilogue: tanh + V-dot, reduce over this block's 128 u's
    const int b = row0 >> 11;   // 128-row tiles never cross a batch
    float sacc[4][4];
    for (int tr = 0; tr < 4; ++tr)
        for (int r = 0; r < 4; ++r) sacc[tr][r] = 0.f;

    for (int tc = 0; tc < 4; ++tc) {
        int u_g   = col0 + wn * 64 + tc * 16 + l15;
        float pdv = pd[b * DIM + u_g];
        float vv  = V[u_g];
        for (int tr = 0; tr < 4; ++tr)
            for (int r = 0; r < 4; ++r)
                sacc[tr][r] += tanhf(acc[tr][tc][r] + pdv) * vv;
    }
    for (int tr = 0; tr < 4; ++tr)
        for (int r = 0; r < 4; ++r) {
            float v = sacc[tr][r];
            v += __shfl_xor(v, 1);
            v += __shfl_xor(v, 2);
            v += __shfl_xor(v, 4);
            v += __shfl_xor(v, 8);
            sacc[tr][r] = v;
        }
    if (l15 == 0) {
        for (int tr = 0; tr < 4; ++tr)
            for (int r = 0; r < 4; ++r) {
                int m_g = row0 + wm * 64 + tr * 16 + quad * 4 + r;
                atomicAdd(&scores[m_g], sacc[tr][r]);
            }
    }
}

// ---------------------------------------------------------------------------
// Kernel 2 (fallback, ws too small): round-1 fp32-staging GEMM
// ---------------------------------------------------------------------------
#define SAS 72
__global__ __launch_bounds__(256, 2) void gemm_score_kernel(
    const float* __restrict__ enc,
    const unsigned short* __restrict__ w1t,
    const float* __restrict__ pd,
    const float* __restrict__ V,
    float* __restrict__ scores)
{
    __shared__ unsigned short sA[BM * SAS];
    __shared__ unsigned short sB[BN * SAS];

    const int tid  = threadIdx.x;
    const int lane = tid & 63;
    const int wave = tid >> 6;
    const int wm   = wave & 1;
    const int wn   = wave >> 1;
    const int quad = lane >> 4;
    const int l15  = lane & 15;

    const int row0 = blockIdx.x * BM;
    const int col0 = blockIdx.y * BN;

    f32x4 acc[4][4];
    for (int i = 0; i < 4; ++i)
        for (int j = 0; j < 4; ++j)
            acc[i][j] = (f32x4){0.f, 0.f, 0.f, 0.f};

    for (int k0 = 0; k0 < DIM; k0 += BK) {
        for (int i = 0; i < 8; ++i) {
            int s  = i * 256 + tid;
            int r  = s >> 4;
            int c4 = s & 15;
            const float4 v = *(const float4*)(enc + (size_t)(row0 + r) * DIM + k0 + c4 * 4);
            ushort4 p;
            p.x = f2bf(v.x); p.y = f2bf(v.y); p.z = f2bf(v.z); p.w = f2bf(v.w);
            *(ushort4*)(&sA[r * SAS + c4 * 4]) = p;
        }
        for (int i = 0; i < 4; ++i) {
            int s  = i * 256 + tid;
            int u  = s >> 3;
            int c8 = s & 7;
            const uint4 w = *(const uint4*)(w1t + (size_t)(col0 + u) * DIM + k0 + c8 * 8);
            *(uint4*)(&sB[u * SAS + c8 * 8]) = w;
        }
        __syncthreads();

        for (int kk = 0; kk < BK; kk += 32) {
            bf16x8 af[4], bfr[4];
            for (int t4 = 0; t4 < 4; ++t4) {
                int am = wm * 64 + t4 * 16 + l15;
                af[t4]  = *(const bf16x8*)(&sA[am * SAS + kk + quad * 8]);
                int bn = wn * 64 + t4 * 16 + l15;
                bfr[t4] = *(const bf16x8*)(&sB[bn * SAS + kk + quad * 8]);
            }
            for (int tr = 0; tr < 4; ++tr)
                for (int tc = 0; tc < 4; ++tc)
                    acc[tr][tc] = __builtin_amdgcn_mfma_f32_16x16x32_bf16(
                        af[tr], bfr[tc], acc[tr][tc], 0, 0, 0);
        }
        __syncthreads();
    }

    const int b = row0 >> 11;
    float sacc[4][4];
    for (int tr = 0; tr < 4; ++tr)
        for (int r = 0; r < 4; ++r) sacc[tr][r] = 0.f;

    for (int tc = 0; tc < 4; ++tc) {
        int u_g   = col0 + wn * 64 + tc * 16 + l15;
        float pdv = pd[b * DIM + u_g];
        float vv  = V[u_g];
        for (int tr = 0; tr < 4; ++tr)
            for (int r = 0; r < 4; ++r)
                sacc[tr][r] += tanhf(acc[tr][tc][r] + pdv) * vv;
    }
    for (int tr = 0; tr < 4; ++tr)
        for (int r = 0; r < 4; ++r) {
            float v = sacc[tr][r];
            v += __shfl_xor(v, 1);
            v += __shfl_xor(v, 2);
            v += __shfl_xor(v, 4);
            v += __shfl_xor(v, 8);
            sacc[tr][r] = v;
        }
    if (l15 == 0) {
        for (int tr = 0; tr < 4; ++tr)
            for (int r = 0; r < 4; ++r) {
                int m_g = row0 + wm * 64 + tr * 16 + quad * 4 + r;
                atomicAdd(&scores[m_g], sacc[tr][r]);
            }
    }
}

// ---------------------------------------------------------------------------
// Kernel 3: per-batch softmax over S=2048 -> attn (output)
// bv omitted: softmax is shift-invariant in both outputs.
// ---------------------------------------------------------------------------
__global__ void softmax_kernel(const float* __restrict__ scores,
                               float* __restrict__ attn) {
    __shared__ float se[SEQ];
    __shared__ float red[256];
    const int b = blockIdx.x;
    const int t = threadIdx.x;
    const float* sc = scores + (size_t)b * SEQ;

    float v[8];
    float mx = -1e30f;
    for (int i = 0; i < 8; ++i) {
        v[i] = sc[t + i * 256];
        mx = fmaxf(mx, v[i]);
    }
    red[t] = mx;
    __syncthreads();
    for (int off = 128; off > 0; off >>= 1) {
        if (t < off) red[t] = fmaxf(red[t], red[t + off]);
        __syncthreads();
    }
    mx = red[0];
    __syncthreads();

    float sum = 0.f;
    for (int i = 0; i < 8; ++i) {
        float e = expf(v[i] - mx);
        se[t + i * 256] = e;
        sum += e;
    }
    red[t] = sum;
    __syncthreads();
    for (int off = 128; off > 0; off >>= 1) {
        if (t < off) red[t] += red[t + off];
        __syncthreads();
    }
    const float inv = 1.0f / red[0];
    for (int i = 0; i < 8; ++i)
        attn[(size_t)b * SEQ + t + i * 256] = se[t + i * 256] * inv;
}

// ---------------------------------------------------------------------------
// Kernel 4 (fast): context from bf16 enc. 16 B loads, 4 rows/iter.
// ---------------------------------------------------------------------------
#define SCHUNK 64
__global__ void context_fast(const unsigned short* __restrict__ encb,
                             const float* __restrict__ attn,
                             float* __restrict__ ctx) {
    __shared__ float sa[SCHUNK];
    __shared__ float sred[256 * 8];
    const int c = blockIdx.x;   // 0..31
    const int b = blockIdx.y;   // 0..63
    const int t = threadIdx.x;  // 256
    if (t < SCHUNK) sa[t] = attn[(size_t)b * SEQ + c * SCHUNK + t];
    __syncthreads();
    const int j2 = t >> 6;          // 0..3
    const int d0 = (t & 63) * 8;    // 8 bf16 per thread
    float a[8];
    for (int q = 0; q < 8; ++q) a[q] = 0.f;
    const unsigned short* base = encb + ((size_t)b * SEQ + (size_t)c * SCHUNK) * DIM;
    for (int it = 0; it < SCHUNK / 4; ++it) {
        int j = it * 4 + j2;
        float w = sa[j];
        bf16x8 v = *(const bf16x8*)(base + (size_t)j * DIM + d0);
        for (int q = 0; q < 8; ++q)
            a[q] += w * bf2f((unsigned short)v[q]);
    }
    for (int q = 0; q < 8; ++q) sred[t * 8 + q] = a[q];
    __syncthreads();
    if (t < 64) {
        for (int q = 0; q < 8; ++q) {
            float s = sred[t * 8 + q] + sred[(t + 64) * 8 + q] +
                      sred[(t + 128) * 8 + q] + sred[(t + 192) * 8 + q];
            atomicAdd(&ctx[b * DIM + t * 8 + q], s);
        }
    }
}

// Fallback context (fp32 enc)
__global__ void context_kernel(const float* __restrict__ enc,
                               const float* __restrict__ attn,
                               float* __restrict__ ctx) {
    __shared__ float sa[SCHUNK];
    const int c = blockIdx.x;
    const int b = blockIdx.y;
    const int t = threadIdx.x;
    if (t < SCHUNK) sa[t] = attn[(size_t)b * SEQ + c * SCHUNK + t];
    __syncthreads();
    float a0 = 0.f, a1 = 0.f;
    const float* base = enc + ((size_t)b * SEQ + (size_t)c * SCHUNK) * DIM;
    for (int j = 0; j < SCHUNK; ++j) {
        float w = sa[j];
        a0 += w * base[(size_t)j * DIM + t];
        a1 += w * base[(size_t)j * DIM + t + 256];
    }
    atomicAdd(&ctx[b * DIM + t], a0);
    atomicAdd(&ctx[b * DIM + t + 256], a1);
}

// ---------------------------------------------------------------------------
// Launch
// ---------------------------------------------------------------------------
extern "C" void kernel_launch(void* const* d_in, const int* in_sizes, int n_in,
                              void* d_out, int out_size, void* d_ws, size_t ws_size,
                              hipStream_t stream) {
    const float* enc = (const float*)d_in[0];   // [64,2048,512]
    const float* dec = (const float*)d_in[1];   // [64,512]
    const float* W1  = (const float*)d_in[2];   // [512,512]
    const float* b1  = (const float*)d_in[3];   // [512]
    const float* W2  = (const float*)d_in[4];   // [512,512]
    const float* b2  = (const float*)d_in[5];   // [512]
    const float* V   = (const float*)d_in[6];   // [512,1]
    // d_in[7] = bv: dead (softmax shift-invariance)

    float* out  = (float*)d_out;
    float* ctx  = out;                 // [64,512]
    float* attn = out + BATCH * DIM;   // [64,2048]

    const size_t ENCB_BYTES = (size_t)MROWS * DIM * 2;   // 134 MB
    const size_t need = ENCB_BYTES + 131072 + 524288 + 524288;

    char* ws = (char*)d_ws;

    if (ws_size >= need) {
        unsigned short* encb = (unsigned short*)ws;
        float* pd            = (float*)(ws + ENCB_BYTES);
        unsigned short* w1t  = (unsigned short*)(ws + ENCB_BYTES + 131072);
        float* scores        = (float*)(ws + ENCB_BYTES + 131072 + 524288);

        hipMemsetAsync(scores, 0, (size_t)MROWS * 4, stream);
        hipMemsetAsync(ctx, 0, (size_t)BATCH * DIM * 4, stream);

        conv_enc_kernel<<<4096, 256, 0, stream>>>(enc, encb);
        prep_w1t_kernel<<<256, 256, 0, stream>>>(W1, w1t);
        proj_dec_kernel<<<BATCH, 256, 0, stream>>>(dec, W2, b1, b2, pd);
        gemm_score_fast<<<dim3(DIM / BN, MROWS / BM), 256, 0, stream>>>(
            encb, w1t, pd, V, scores);
        softmax_kernel<<<BATCH, 256, 0, stream>>>(scores, attn);
        context_fast<<<dim3(SEQ / SCHUNK, BATCH), 256, 0, stream>>>(encb, attn, ctx);
    } else {
        float* pd            = (float*)ws;
        unsigned short* w1t  = (unsigned short*)(ws + 131072);
        float* scores        = (float*)(ws + 131072 + 524288);

        hipMemsetAsync(scores, 0, (size_t)MROWS * 4, stream);
        hipMemsetAsync(ctx, 0, (size_t)BATCH * DIM * 4, stream);

        prep_w1t_kernel<<<256, 256, 0, stream>>>(W1, w1t);
        proj_dec_kernel<<<BATCH, 256, 0, stream>>>(dec, W2, b1, b2, pd);
        gemm_score_kernel<<<dim3(MROWS / BM, DIM / BN), 256, 0, stream>>>(
            enc, w1t, pd, V, scores);
        softmax_kernel<<<BATCH, 256, 0, stream>>>(scores, attn);
        context_kernel<<<dim3(SEQ / SCHUNK, BATCH), 256, 0, stream>>>(enc, attn, ctx);
    }
}

// Round 3
// 558.984 us; speedup vs baseline: 1.1681x; 1.0603x over previous
//
#include <hip/hip_runtime.h>
#include <hip/hip_bf16.h>

// Problem constants (from reference): B=64, S=2048, D_ENC=D_DEC=UNITS=512
#define BATCH 64
#define SEQ   2048
#define DIM   512
#define MROWS (BATCH * SEQ)   // 131072 rows of the big GEMM

typedef short bf16x8 __attribute__((ext_vector_type(8)));
typedef float f32x4  __attribute__((ext_vector_type(4)));

static __device__ __forceinline__ unsigned short f2bf(float f) {
    // round-to-nearest-even fp32 -> bf16
    union { float f; unsigned u; } v; v.f = f;
    unsigned u = v.u;
    u += 0x7FFFu + ((u >> 16) & 1u);
    return (unsigned short)(u >> 16);
}
static __device__ __forceinline__ float bf2f(unsigned short h) {
    union { unsigned u; float f; } v; v.u = ((unsigned)h) << 16; return v.f;
}

// fast tanh: tanh(x) = (e^{2x}-1)/(e^{2x}+1), e^{2x} = 2^{x*2log2(e)}
static __device__ __forceinline__ float tanh_fast(float x) {
    float xc = fminf(20.0f, fmaxf(-20.0f, x));
#if __has_builtin(__builtin_amdgcn_exp2f)
    float t = __builtin_amdgcn_exp2f(2.885390082f * xc);
#else
    float t = exp2f(2.885390082f * xc);
#endif
#if __has_builtin(__builtin_amdgcn_rcpf)
    return (t - 1.0f) * __builtin_amdgcn_rcpf(t + 1.0f);
#else
    return (t - 1.0f) / (t + 1.0f);
#endif
}

// global -> LDS async DMA, 16B per lane. LDS dest must be wave-uniform base
// + lane*16 (m104/m108 caveat) — our chunk ids are lane-consecutive.
typedef __attribute__((address_space(1))) const unsigned int gu32;
typedef __attribute__((address_space(3))) unsigned int lu32;
static __device__ __forceinline__ void gload_lds16(const unsigned short* g,
                                                   unsigned short* l) {
    __builtin_amdgcn_global_load_lds((gu32*)g, (lu32*)l, 16, 0, 0);
}

// ---------------------------------------------------------------------------
// Kernel 0: W1 [k][u] fp32  ->  W1t [u][k] bf16   (512x512, tiny)
// ---------------------------------------------------------------------------
__global__ void prep_w1t_kernel(const float* __restrict__ W1,
                                unsigned short* __restrict__ w1t) {
    int stride = gridDim.x * blockDim.x;
    for (int i = blockIdx.x * blockDim.x + threadIdx.x; i < DIM * DIM; i += stride) {
        int k = i >> 9;
        int u = i & 511;
        w1t[u * DIM + k] = f2bf(W1[i]);
    }
}

// ---------------------------------------------------------------------------
// Kernel 0b: enc fp32 -> encb bf16 (pure-BW pass: 268 MB R + 134 MB W)
// ---------------------------------------------------------------------------
__global__ void conv_enc_kernel(const float* __restrict__ enc,
                                unsigned short* __restrict__ encb) {
    const size_t nunits = (size_t)MROWS * DIM / 8;  // 8 elems per unit
    size_t stride = (size_t)gridDim.x * blockDim.x;
    for (size_t u = (size_t)blockIdx.x * blockDim.x + threadIdx.x; u < nunits;
         u += stride) {
        const float4* p = (const float4*)(enc + u * 8);
        float4 a = p[0], b = p[1];
        union { ushort4 s[2]; uint4 q; } o;
        o.s[0].x = f2bf(a.x); o.s[0].y = f2bf(a.y);
        o.s[0].z = f2bf(a.z); o.s[0].w = f2bf(a.w);
        o.s[1].x = f2bf(b.x); o.s[1].y = f2bf(b.y);
        o.s[1].z = f2bf(b.z); o.s[1].w = f2bf(b.w);
        *(uint4*)(encb + u * 8) = o.q;
    }
}

// ---------------------------------------------------------------------------
// Kernel 1: pd[b][u] = dec[b,:] @ W2[:,u] + b1[u] + b2[u]     (64x512, tiny)
// ---------------------------------------------------------------------------
__global__ void proj_dec_kernel(const float* __restrict__ dec,
                                const float* __restrict__ W2,
                                const float* __restrict__ b1,
                                const float* __restrict__ b2,
                                float* __restrict__ pd) {
    __shared__ float sdec[DIM];
    const int b = blockIdx.x;
    const int t = threadIdx.x;          // 256 threads
    sdec[t]       = dec[b * DIM + t];
    sdec[t + 256] = dec[b * DIM + t + 256];
    __syncthreads();
    const int u0 = t, u1 = t + 256;
    float a0 = b1[u0] + b2[u0];
    float a1 = b1[u1] + b2[u1];
    for (int k = 0; k < DIM; ++k) {
        float dk = sdec[k];
        a0 += dk * W2[k * DIM + u0];
        a1 += dk * W2[k * DIM + u1];
    }
    pd[b * DIM + u0] = a0;
    pd[b * DIM + u1] = a1;
}

// ---------------------------------------------------------------------------
// Kernel 2 (v3): block = 64 rows x FULL N=512. Each of 4 waves owns one
// 128-col strip. Per K-round (BK=64): stage sA 8 KB + sB 64 KB (all 512 u's)
// via global_load_lds w/ XOR chunk swizzle; 256 MFMA per block per barrier
// pair. A is fetched exactly once (no col-sibling re-fetch); B (512 KB) is
// shared by all 2048 blocks -> L2-resident. Epilogue: fast tanh + V-dot,
// shuffle reduce, cross-wave LDS reduce, direct scores store (no atomics).
// LDS 72 KB -> 2 blocks/CU.
// ---------------------------------------------------------------------------
#define BM3 64
#define BK3 64

__global__ __launch_bounds__(256, 2) void gemm_score_v3(
    const unsigned short* __restrict__ encb,  // [m][k] bf16
    const unsigned short* __restrict__ w1t,   // [u][k] bf16
    const float* __restrict__ pd,             // [b][u]
    const float* __restrict__ V,              // [u]
    float* __restrict__ scores)               // [M]
{
    __shared__ unsigned short sA[BM3 * BK3];   // 8 KB
    __shared__ unsigned short sB[DIM * BK3];   // 64 KB

    const int tid  = threadIdx.x;
    const int lane = tid & 63;
    const int wave = tid >> 6;        // 0..3 -> col strip wave*128
    const int quad = lane >> 4;
    const int l15  = lane & 15;

    const int row0 = blockIdx.x * BM3;   // gridDim.x = 2048

    f32x4 acc[8][4];   // [j: col subtile 16][tr: row subtile 16]
    for (int j = 0; j < 8; ++j)
        for (int tr = 0; tr < 4; ++tr)
            acc[j][tr] = (f32x4){0.f, 0.f, 0.f, 0.f};

    for (int k0 = 0; k0 < DIM; k0 += BK3) {
        // stage A: 64 rows x 64 k = 512 chunks of 16 B, 2/thread
        for (int i = 0; i < 2; ++i) {
            int c  = i * 256 + tid;
            int r  = c >> 3;
            int cc = c & 7;
            int gc = cc ^ (r & 7);
            gload_lds16(encb + (size_t)(row0 + r) * DIM + k0 + gc * 8, &sA[c * 8]);
        }
        // stage B: 512 u's x 64 k = 4096 chunks of 16 B, 16/thread
        for (int i = 0; i < 16; ++i) {
            int c  = i * 256 + tid;
            int r  = c >> 3;          // u = 0..511
            int cc = c & 7;
            int gc = cc ^ (r & 7);
            gload_lds16(w1t + (size_t)r * DIM + k0 + gc * 8, &sB[c * 8]);
        }
        __syncthreads();

        for (int kk = 0; kk < BK3; kk += 32) {
            int jc = (kk >> 3) + quad;   // global k-chunk 0..7
            bf16x8 af[4];
            for (int tr = 0; tr < 4; ++tr) {
                int am = tr * 16 + l15;
                af[tr] = *(const bf16x8*)(&sA[am * BK3 + ((jc ^ (am & 7)) * 8)]);
            }
            for (int j = 0; j < 8; ++j) {
                int u = wave * 128 + j * 16 + l15;
                bf16x8 bfr = *(const bf16x8*)(&sB[u * BK3 + ((jc ^ (u & 7)) * 8)]);
                for (int tr = 0; tr < 4; ++tr)
                    acc[j][tr] = __builtin_amdgcn_mfma_f32_16x16x32_bf16(
                        af[tr], bfr, acc[j][tr], 0, 0, 0);
            }
        }
        __syncthreads();
    }

    // epilogue: tanh + V-dot over this wave's 128 u's
    const int b = row0 >> 11;   // 64-row blocks never cross a batch
    float sacc[4][4];
    for (int tr = 0; tr < 4; ++tr)
        for (int r = 0; r < 4; ++r) sacc[tr][r] = 0.f;

    for (int j = 0; j < 8; ++j) {
        int u_g   = wave * 128 + j * 16 + l15;
        float pdv = pd[b * DIM + u_g];
        float vv  = V[u_g];
        for (int tr = 0; tr < 4; ++tr)
            for (int r = 0; r < 4; ++r)
                sacc[tr][r] += tanh_fast(acc[j][tr][r] + pdv) * vv;
    }
    // reduce across the 16 col-lanes (lane bits 0..3)
    for (int tr = 0; tr < 4; ++tr)
        for (int r = 0; r < 4; ++r) {
            float v = sacc[tr][r];
            v += __shfl_xor(v, 1);
            v += __shfl_xor(v, 2);
            v += __shfl_xor(v, 4);
            v += __shfl_xor(v, 8);
            sacc[tr][r] = v;
        }
    // cross-wave reduce via LDS (reuse sA space)
    float* red = (float*)sA;   // 4 waves x 64 rows = 1 KB
    if (l15 == 0) {
        for (int tr = 0; tr < 4; ++tr)
            for (int r = 0; r < 4; ++r)
                red[wave * BM3 + tr * 16 + quad * 4 + r] = sacc[tr][r];
    }
    __syncthreads();
    if (tid < BM3) {
        float s = red[tid] + red[BM3 + tid] + red[2 * BM3 + tid] + red[3 * BM3 + tid];
        scores[row0 + tid] = s;
    }
}

// ---------------------------------------------------------------------------
// Kernel 2 (fallback, ws too small): round-1 fp32-staging GEMM (atomics)
// ---------------------------------------------------------------------------
#define BM 128
#define BN 128
#define BK 64
#define SAS 72
__global__ __launch_bounds__(256, 2) void gemm_score_kernel(
    const float* __restrict__ enc,
    const unsigned short* __restrict__ w1t,
    const float* __restrict__ pd,
    const float* __restrict__ V,
    float* __restrict__ scores)
{
    __shared__ unsigned short sA[BM * SAS];
    __shared__ unsigned short sB[BN * SAS];

    const int tid  = threadIdx.x;
    const int lane = tid & 63;
    const int wave = tid >> 6;
    const int wm   = wave & 1;
    const int wn   = wave >> 1;
    const int quad = lane >> 4;
    const int l15  = lane & 15;

    const int row0 = blockIdx.x * BM;
    const int col0 = blockIdx.y * BN;

    f32x4 acc[4][4];
    for (int i = 0; i < 4; ++i)
        for (int j = 0; j < 4; ++j)
            acc[i][j] = (f32x4){0.f, 0.f, 0.f, 0.f};

    for (int k0 = 0; k0 < DIM; k0 += BK) {
        for (int i = 0; i < 8; ++i) {
            int s  = i * 256 + tid;
            int r  = s >> 4;
            int c4 = s & 15;
            const float4 v = *(const float4*)(enc + (size_t)(row0 + r) * DIM + k0 + c4 * 4);
            ushort4 p;
            p.x = f2bf(v.x); p.y = f2bf(v.y); p.z = f2bf(v.z); p.w = f2bf(v.w);
            *(ushort4*)(&sA[r * SAS + c4 * 4]) = p;
        }
        for (int i = 0; i < 4; ++i) {
            int s  = i * 256 + tid;
            int u  = s >> 3;
            int c8 = s & 7;
            const uint4 w = *(const uint4*)(w1t + (size_t)(col0 + u) * DIM + k0 + c8 * 8);
            *(uint4*)(&sB[u * SAS + c8 * 8]) = w;
        }
        __syncthreads();

        for (int kk = 0; kk < BK; kk += 32) {
            bf16x8 af[4], bfr[4];
            for (int t4 = 0; t4 < 4; ++t4) {
                int am = wm * 64 + t4 * 16 + l15;
                af[t4]  = *(const bf16x8*)(&sA[am * SAS + kk + quad * 8]);
                int bn = wn * 64 + t4 * 16 + l15;
                bfr[t4] = *(const bf16x8*)(&sB[bn * SAS + kk + quad * 8]);
            }
            for (int tr = 0; tr < 4; ++tr)
                for (int tc = 0; tc < 4; ++tc)
                    acc[tr][tc] = __builtin_amdgcn_mfma_f32_16x16x32_bf16(
                        af[tr], bfr[tc], acc[tr][tc], 0, 0, 0);
        }
        __syncthreads();
    }

    const int b = row0 >> 11;
    float sacc[4][4];
    for (int tr = 0; tr < 4; ++tr)
        for (int r = 0; r < 4; ++r) sacc[tr][r] = 0.f;

    for (int tc = 0; tc < 4; ++tc) {
        int u_g   = col0 + wn * 64 + tc * 16 + l15;
        float pdv = pd[b * DIM + u_g];
        float vv  = V[u_g];
        for (int tr = 0; tr < 4; ++tr)
            for (int r = 0; r < 4; ++r)
                sacc[tr][r] += tanh_fast(acc[tr][tc][r] + pdv) * vv;
    }
    for (int tr = 0; tr < 4; ++tr)
        for (int r = 0; r < 4; ++r) {
            float v = sacc[tr][r];
            v += __shfl_xor(v, 1);
            v += __shfl_xor(v, 2);
            v += __shfl_xor(v, 4);
            v += __shfl_xor(v, 8);
            sacc[tr][r] = v;
        }
    if (l15 == 0) {
        for (int tr = 0; tr < 4; ++tr)
            for (int r = 0; r < 4; ++r) {
                int m_g = row0 + wm * 64 + tr * 16 + quad * 4 + r;
                atomicAdd(&scores[m_g], sacc[tr][r]);
            }
    }
}

// ---------------------------------------------------------------------------
// Kernel 3: per-batch softmax over S=2048 -> attn (output)
// bv omitted: softmax is shift-invariant in both outputs.
// ---------------------------------------------------------------------------
__global__ void softmax_kernel(const float* __restrict__ scores,
                               float* __restrict__ attn) {
    __shared__ float se[SEQ];
    __shared__ float red[256];
    const int b = blockIdx.x;
    const int t = threadIdx.x;
    const float* sc = scores + (size_t)b * SEQ;

    float v[8];
    float mx = -1e30f;
    for (int i = 0; i < 8; ++i) {
        v[i] = sc[t + i * 256];
        mx = fmaxf(mx, v[i]);
    }
    red[t] = mx;
    __syncthreads();
    for (int off = 128; off > 0; off >>= 1) {
        if (t < off) red[t] = fmaxf(red[t], red[t + off]);
        __syncthreads();
    }
    mx = red[0];
    __syncthreads();

    float sum = 0.f;
    for (int i = 0; i < 8; ++i) {
        float e = expf(v[i] - mx);
        se[t + i * 256] = e;
        sum += e;
    }
    red[t] = sum;
    __syncthreads();
    for (int off = 128; off > 0; off >>= 1) {
        if (t < off) red[t] += red[t + off];
        __syncthreads();
    }
    const float inv = 1.0f / red[0];
    for (int i = 0; i < 8; ++i)
        attn[(size_t)b * SEQ + t + i * 256] = se[t + i * 256] * inv;
}

// ---------------------------------------------------------------------------
// Kernel 4 (fast): context from bf16 enc. 16 B loads, 4 rows/iter.
// ---------------------------------------------------------------------------
#define SCHUNK 64
__global__ void context_fast(const unsigned short* __restrict__ encb,
                             const float* __restrict__ attn,
                             float* __restrict__ ctx) {
    __shared__ float sa[SCHUNK];
    __shared__ float sred[256 * 8];
    const int c = blockIdx.x;   // 0..31
    const int b = blockIdx.y;   // 0..63
    const int t = threadIdx.x;  // 256
    if (t < SCHUNK) sa[t] = attn[(size_t)b * SEQ + c * SCHUNK + t];
    __syncthreads();
    const int j2 = t >> 6;          // 0..3
    const int d0 = (t & 63) * 8;    // 8 bf16 per thread
    float a[8];
    for (int q = 0; q < 8; ++q) a[q] = 0.f;
    const unsigned short* base = encb + ((size_t)b * SEQ + (size_t)c * SCHUNK) * DIM;
    for (int it = 0; it < SCHUNK / 4; ++it) {
        int j = it * 4 + j2;
        float w = sa[j];
        bf16x8 v = *(const bf16x8*)(base + (size_t)j * DIM + d0);
        for (int q = 0; q < 8; ++q)
            a[q] += w * bf2f((unsigned short)v[q]);
    }
    for (int q = 0; q < 8; ++q) sred[t * 8 + q] = a[q];
    __syncthreads();
    if (t < 64) {
        for (int q = 0; q < 8; ++q) {
            float s = sred[t * 8 + q] + sred[(t + 64) * 8 + q] +
                      sred[(t + 128) * 8 + q] + sred[(t + 192) * 8 + q];
            atomicAdd(&ctx[b * DIM + t * 8 + q], s);
        }
    }
}

// Fallback context (fp32 enc)
__global__ void context_kernel(const float* __restrict__ enc,
                               const float* __restrict__ attn,
                               float* __restrict__ ctx) {
    __shared__ float sa[SCHUNK];
    const int c = blockIdx.x;
    const int b = blockIdx.y;
    const int t = threadIdx.x;
    if (t < SCHUNK) sa[t] = attn[(size_t)b * SEQ + c * SCHUNK + t];
    __syncthreads();
    float a0 = 0.f, a1 = 0.f;
    const float* base = enc + ((size_t)b * SEQ + (size_t)c * SCHUNK) * DIM;
    for (int j = 0; j < SCHUNK; ++j) {
        float w = sa[j];
        a0 += w * base[(size_t)j * DIM + t];
        a1 += w * base[(size_t)j * DIM + t + 256];
    }
    atomicAdd(&ctx[b * DIM + t], a0);
    atomicAdd(&ctx[b * DIM + t + 256], a1);
}

// ---------------------------------------------------------------------------
// Launch
// ---------------------------------------------------------------------------
extern "C" void kernel_launch(void* const* d_in, const int* in_sizes, int n_in,
                              void* d_out, int out_size, void* d_ws, size_t ws_size,
                              hipStream_t stream) {
    const float* enc = (const float*)d_in[0];   // [64,2048,512]
    const float* dec = (const float*)d_in[1];   // [64,512]
    const float* W1  = (const float*)d_in[2];   // [512,512]
    const float* b1  = (const float*)d_in[3];   // [512]
    const float* W2  = (const float*)d_in[4];   // [512,512]
    const float* b2  = (const float*)d_in[5];   // [512]
    const float* V   = (const float*)d_in[6];   // [512,1]
    // d_in[7] = bv: dead (softmax shift-invariance)

    float* out  = (float*)d_out;
    float* ctx  = out;                 // [64,512]
    float* attn = out + BATCH * DIM;   // [64,2048]

    const size_t ENCB_BYTES = (size_t)MROWS * DIM * 2;   // 134 MB
    const size_t need = ENCB_BYTES + 131072 + 524288 + 524288;

    char* ws = (char*)d_ws;

    if (ws_size >= need) {
        unsigned short* encb = (unsigned short*)ws;
        float* pd            = (float*)(ws + ENCB_BYTES);
        unsigned short* w1t  = (unsigned short*)(ws + ENCB_BYTES + 131072);
        float* scores        = (float*)(ws + ENCB_BYTES + 131072 + 524288);

        hipMemsetAsync(ctx, 0, (size_t)BATCH * DIM * 4, stream);

        prep_w1t_kernel<<<256, 256, 0, stream>>>(W1, w1t);
        proj_dec_kernel<<<BATCH, 256, 0, stream>>>(dec, W2, b1, b2, pd);
        conv_enc_kernel<<<4096, 256, 0, stream>>>(enc, encb);
        gemm_score_v3<<<MROWS / BM3, 256, 0, stream>>>(encb, w1t, pd, V, scores);
        softmax_kernel<<<BATCH, 256, 0, stream>>>(scores, attn);
        context_fast<<<dim3(SEQ / SCHUNK, BATCH), 256, 0, stream>>>(encb, attn, ctx);
    } else {
        float* pd            = (float*)ws;
        unsigned short* w1t  = (unsigned short*)(ws + 131072);
        float* scores        = (float*)(ws + 131072 + 524288);

        hipMemsetAsync(scores, 0, (size_t)MROWS * 4, stream);
        hipMemsetAsync(ctx, 0, (size_t)BATCH * DIM * 4, stream);

        prep_w1t_kernel<<<256, 256, 0, stream>>>(W1, w1t);
        proj_dec_kernel<<<BATCH, 256, 0, stream>>>(dec, W2, b1, b2, pd);
        gemm_score_kernel<<<dim3(MROWS / BM, DIM / BN), 256, 0, stream>>>(
            enc, w1t, pd, V, scores);
        softmax_kernel<<<BATCH, 256, 0, stream>>>(scores, attn);
        context_kernel<<<dim3(SEQ / SCHUNK, BATCH), 256, 0, stream>>>(enc, attn, ctx);
    }
}